// Round 10
// baseline (141.572 us; speedup 1.0000x reference)
//
#include <hip/hip_runtime.h>

#define UNITS 64
#define NNODES 50000
#define NBUCK 512          // bucket = row*512/50000, 97-98 rows each
#define CAP 3584           // records per bucket region (mean 3125, sigma ~56 -> +8 sigma)
#define BIN_TPB 512
#define BIN_EPT 8          // 4096 edges per bin block -> 391 blocks
#define SPMM_TPB 1024
#define MAXROWS 98
#define FXSCALE 67108864.0f        // 2^26
#define FXINV   1.4901161193847656e-8f  // 2^-26

typedef unsigned long long u64;
typedef unsigned int u32;
typedef unsigned short u16;

// ---------------- workspace layout (bytes) ----------------
// kb      : [0,        6400000)   3.2M bf16 (kernel cast)
// gcursor : [6400000,  6402048)   512 ints
// edges   : [6402048,  6402048 + NBUCK*CAP*8 = 14.68MB)  packed records:
//           bits[63:32]=value*2^26 (f32), [31:23]=bucket, [22:16]=row-in-bucket, [15:0]=col

__device__ __forceinline__ int rowbase_of(u32 b) {
    return (int)((b * 50000u + 511u) >> 9);   // ceil(b*50000/512)
}

// f32 -> bf16 (RN) convert, fused with gcursor init
__global__ void gc_prep(const float* __restrict__ kf, u16* __restrict__ kb,
                        int* __restrict__ gcursor, int n4) {
    int i = blockIdx.x * blockDim.x + threadIdx.x;
    if (blockIdx.x == 0 && threadIdx.x < 256) {
        gcursor[threadIdx.x]       = threadIdx.x * CAP;
        gcursor[threadIdx.x + 256] = (threadIdx.x + 256) * CAP;
    }
    if (i >= n4) return;
    float4 f = ((const float4*)kf)[i];
    ushort4 o;
    u32 b;
    b = __float_as_uint(f.x); o.x = (u16)((b + 0x7FFFu + ((b >> 16) & 1u)) >> 16);
    b = __float_as_uint(f.y); o.y = (u16)((b + 0x7FFFu + ((b >> 16) & 1u)) >> 16);
    b = __float_as_uint(f.z); o.z = (u16)((b + 0x7FFFu + ((b >> 16) & 1u)) >> 16);
    b = __float_as_uint(f.w); o.w = (u16)((b + 0x7FFFu + ((b >> 16) & 1u)) >> 16);
    ((ushort4*)kb)[i] = o;
}

// Bin edges into padded per-bucket regions with coalesced writes.
// Each thread owns 8 CONSECUTIVE edges -> int4/float4 vector input loads.
__global__ __launch_bounds__(BIN_TPB) void gc_bin(const int* __restrict__ rows,
                                                  const int* __restrict__ cols,
                                                  const float* __restrict__ values,
                                                  int* __restrict__ gcursor,
                                                  u64* __restrict__ edges, int nnz) {
    __shared__ u64 stage[BIN_TPB * BIN_EPT];   // 32 KB
    __shared__ int hist[NBUCK];
    __shared__ int lstart[NBUCK];
    __shared__ int delta[NBUCK];
    __shared__ int wsum[8];
    int t = threadIdx.x;
    hist[t] = 0;
    __syncthreads();

    int blockStart = blockIdx.x * (BIN_TPB * BIN_EPT);
    int cnt = min(BIN_TPB * BIN_EPT, nnz - blockStart);
    int base_idx = blockStart + t * BIN_EPT;

    int rr[BIN_EPT];
    int cc[BIN_EPT];
    float vv[BIN_EPT];
    if (base_idx + BIN_EPT <= nnz) {
        int4 ra = ((const int4*)(rows + base_idx))[0];
        int4 rb = ((const int4*)(rows + base_idx))[1];
        int4 ca = ((const int4*)(cols + base_idx))[0];
        int4 cb = ((const int4*)(cols + base_idx))[1];
        float4 va = ((const float4*)(values + base_idx))[0];
        float4 vb = ((const float4*)(values + base_idx))[1];
        rr[0]=ra.x; rr[1]=ra.y; rr[2]=ra.z; rr[3]=ra.w;
        rr[4]=rb.x; rr[5]=rb.y; rr[6]=rb.z; rr[7]=rb.w;
        cc[0]=ca.x; cc[1]=ca.y; cc[2]=ca.z; cc[3]=ca.w;
        cc[4]=cb.x; cc[5]=cb.y; cc[6]=cb.z; cc[7]=cb.w;
        vv[0]=va.x; vv[1]=va.y; vv[2]=va.z; vv[3]=va.w;
        vv[4]=vb.x; vv[5]=vb.y; vv[6]=vb.z; vv[7]=vb.w;
    } else {
#pragma unroll
        for (int k = 0; k < BIN_EPT; ++k) {
            int idx = base_idx + k;
            rr[k] = (idx < nnz) ? rows[idx] : -1;
            cc[k] = (idx < nnz) ? cols[idx] : 0;
            vv[k] = (idx < nnz) ? values[idx] : 0.0f;
        }
    }

    u64 rec[BIN_EPT];
    int bk[BIN_EPT];
    int rk[BIN_EPT];
#pragma unroll
    for (int k = 0; k < BIN_EPT; ++k) {
        if (rr[k] >= 0) {
            int r = rr[k];
            u32 v = __float_as_uint(vv[k] * FXSCALE);   // pre-scaled value
            int b = (int)(((u32)r * 512u) / 50000u);
            int lrow = r - rowbase_of((u32)b);
            rec[k] = ((u64)v << 32) | ((u64)(u32)b << 23) | ((u64)(u32)lrow << 16) | (u64)(u32)cc[k];
            bk[k] = b;
            rk[k] = atomicAdd(&hist[b], 1);   // native ds_add
        } else {
            bk[k] = -1;
        }
    }
    __syncthreads();

    // shuffle-based exclusive scan of hist[0..512) -> lstart (8 waves x 64)
    {
        int wid = t >> 6, ln = t & 63;
        int val = hist[t];
        for (int off = 1; off < 64; off <<= 1) {
            int x = __shfl_up(val, off, 64);
            if (ln >= off) val += x;
        }
        if (ln == 63) wsum[wid] = val;
        __syncthreads();
        if (t == 0) {
            int s = 0;
            for (int i = 0; i < 8; ++i) { int x = wsum[i]; wsum[i] = s; s += x; }
        }
        __syncthreads();
        int incl = val + wsum[wid];
        int excl = incl - hist[t];
        int h = hist[t];
        int gbase = (h > 0) ? atomicAdd(&gcursor[t], h) : 0;
        delta[t] = gbase - excl;
        lstart[t] = excl;
    }
    __syncthreads();

#pragma unroll
    for (int k = 0; k < BIN_EPT; ++k) {
        if (bk[k] >= 0) stage[lstart[bk[k]] + rk[k]] = rec[k];
    }
    __syncthreads();

    for (int i = t; i < cnt; i += BIN_TPB) {
        u64 r = stage[i];
        int b = (int)((r >> 23) & 0x1FF);
        int gpos = delta[b] + i;
        if (gpos < (b + 1) * CAP) edges[gpos] = r;   // overflow insurance
    }
}

// One block per bucket. Fixed-point i32 out-tile in LDS, accumulated with
// NATIVE int LDS atomics (ds_add_u32, fire-and-forget). Wave per edge,
// lane per unit; bf16 gather; unroll x8 for MLP. No sorting needed.
__global__ __launch_bounds__(SPMM_TPB) void gc_spmm(const u64* __restrict__ edges,
                                                    const int* __restrict__ gcursor,
                                                    const u16* __restrict__ kb,
                                                    const float* __restrict__ bias,
                                                    float* __restrict__ out) {
    __shared__ int tile[MAXROWS * UNITS];   // 25 KB
    int b = blockIdx.x;
    int t = threadIdx.x;
    int rowlo = rowbase_of((u32)b);
    int nrows = rowbase_of((u32)b + 1u) - rowlo;   // 97 or 98
    int count = min(gcursor[b] - b * CAP, CAP);
    const u64* eb = edges + (size_t)b * CAP;

    int total = nrows * UNITS;
    for (int i = t; i < total; i += SPMM_TPB) tile[i] = 0;
    __syncthreads();

    int lane = t & 63;
    int w = t >> 6;                        // 16 waves
    int chunk = (count + 15) >> 4;
    int j   = w * chunk;
    int jhi = min(j + chunk, count);

    for (; j + 8 <= jhi; j += 8) {
        u64 r0 = eb[j + 0], r1 = eb[j + 1], r2 = eb[j + 2], r3 = eb[j + 3];
        u64 r4 = eb[j + 4], r5 = eb[j + 5], r6 = eb[j + 6], r7 = eb[j + 7];
        float k0 = __uint_as_float((u32)kb[((u32)r0 & 0xFFFFu) * UNITS + lane] << 16);
        float k1 = __uint_as_float((u32)kb[((u32)r1 & 0xFFFFu) * UNITS + lane] << 16);
        float k2 = __uint_as_float((u32)kb[((u32)r2 & 0xFFFFu) * UNITS + lane] << 16);
        float k3 = __uint_as_float((u32)kb[((u32)r3 & 0xFFFFu) * UNITS + lane] << 16);
        float k4 = __uint_as_float((u32)kb[((u32)r4 & 0xFFFFu) * UNITS + lane] << 16);
        float k5 = __uint_as_float((u32)kb[((u32)r5 & 0xFFFFu) * UNITS + lane] << 16);
        float k6 = __uint_as_float((u32)kb[((u32)r6 & 0xFFFFu) * UNITS + lane] << 16);
        float k7 = __uint_as_float((u32)kb[((u32)r7 & 0xFFFFu) * UNITS + lane] << 16);
        atomicAdd(&tile[(int)((r0 >> 16) & 0x7F) * UNITS + lane],
                  __float2int_rn(__uint_as_float((u32)(r0 >> 32)) * k0));
        atomicAdd(&tile[(int)((r1 >> 16) & 0x7F) * UNITS + lane],
                  __float2int_rn(__uint_as_float((u32)(r1 >> 32)) * k1));
        atomicAdd(&tile[(int)((r2 >> 16) & 0x7F) * UNITS + lane],
                  __float2int_rn(__uint_as_float((u32)(r2 >> 32)) * k2));
        atomicAdd(&tile[(int)((r3 >> 16) & 0x7F) * UNITS + lane],
                  __float2int_rn(__uint_as_float((u32)(r3 >> 32)) * k3));
        atomicAdd(&tile[(int)((r4 >> 16) & 0x7F) * UNITS + lane],
                  __float2int_rn(__uint_as_float((u32)(r4 >> 32)) * k4));
        atomicAdd(&tile[(int)((r5 >> 16) & 0x7F) * UNITS + lane],
                  __float2int_rn(__uint_as_float((u32)(r5 >> 32)) * k5));
        atomicAdd(&tile[(int)((r6 >> 16) & 0x7F) * UNITS + lane],
                  __float2int_rn(__uint_as_float((u32)(r6 >> 32)) * k6));
        atomicAdd(&tile[(int)((r7 >> 16) & 0x7F) * UNITS + lane],
                  __float2int_rn(__uint_as_float((u32)(r7 >> 32)) * k7));
    }
    for (; j < jhi; ++j) {
        u64 r = eb[j];
        float k = __uint_as_float((u32)kb[((u32)r & 0xFFFFu) * UNITS + lane] << 16);
        atomicAdd(&tile[(int)((r >> 16) & 0x7F) * UNITS + lane],
                  __float2int_rn(__uint_as_float((u32)(r >> 32)) * k));
    }
    __syncthreads();

    float bl = bias[t & 63];   // stride 1024 is a multiple of 64
    for (int i = t; i < total; i += SPMM_TPB) {
        float acc = (float)tile[i] * FXINV + bl;
        out[(size_t)rowlo * UNITS + i] = fmaxf(acc, 0.0f);
    }
}

extern "C" void kernel_launch(void* const* d_in, const int* in_sizes, int n_in,
                              void* d_out, int out_size, void* d_ws, size_t ws_size,
                              hipStream_t stream) {
    const int*   rows   = (const int*)d_in[0];
    const int*   cols   = (const int*)d_in[1];
    const float* values = (const float*)d_in[2];
    const float* kern   = (const float*)d_in[3];
    const float* bias   = (const float*)d_in[4];
    float* out = (float*)d_out;

    const int nnz = in_sizes[0];

    char* ws = (char*)d_ws;
    u16* kb      = (u16*)(ws + 0);
    int* gcursor = (int*)(ws + 6400000);
    u64* edges   = (u64*)(ws + 6402048);

    int n4 = (NNODES * UNITS) / 4;  // 800000
    gc_prep<<<(n4 + 255) / 256, 256, 0, stream>>>(kern, kb, gcursor, n4);

    gc_bin<<<(nnz + BIN_TPB * BIN_EPT - 1) / (BIN_TPB * BIN_EPT), BIN_TPB, 0, stream>>>(
        rows, cols, values, gcursor, edges, nnz);

    gc_spmm<<<NBUCK, SPMM_TPB, 0, stream>>>(edges, gcursor, kb, bias, out);
}

// Round 11
// 116.707 us; speedup vs baseline: 1.2131x; 1.2131x over previous
//
#include <hip/hip_runtime.h>

#define UNITS 64
#define NNODES 50000
#define NBUCK 512          // bucket = row*512/50000, 97-98 rows each
#define CAP 3584           // records per bucket region (mean 3125, sigma ~56 -> +8 sigma)
#define BIN_TPB 512
#define BIN_EPT 8          // 4096 edges per bin block -> 391 bin blocks
#define PREP_BLOCKS 782    // 3.2M floats / (512 thr * 8 floats)
#define SPMM_TPB 1024

typedef unsigned long long u64;
typedef unsigned int u32;
typedef unsigned short u16;

// ---------------- workspace layout (bytes) ----------------
// kb      : [0,        6400000)   3.2M bf16 (kernel cast)
// gcursor : [6400000,  6402048)   512 ints (zeroed by memsetAsync; relative counts)
// edges   : [6402048,  6402048 + NBUCK*CAP*8 = 14.68MB)  packed records:
//           bits[63:32]=value(f32), [31:23]=bucket, [22:16]=row-in-bucket, [15:0]=col

__device__ __forceinline__ int rowbase_of(u32 b) {
    return (int)((b * 50000u + 511u) >> 9);   // ceil(b*50000/512)
}

__device__ __forceinline__ u16 f2bf(u32 b) {
    return (u16)((b + 0x7FFFu + ((b >> 16) & 1u)) >> 16);
}

// Role-split kernel: blocks [0, binBlocks) bin edges into padded per-bucket
// regions with coalesced writes; blocks [binBlocks, ...) convert kernel f32->bf16.
__global__ __launch_bounds__(BIN_TPB) void gc_bin_prep(const int* __restrict__ rows,
                                                       const int* __restrict__ cols,
                                                       const float* __restrict__ values,
                                                       const float* __restrict__ kf,
                                                       u16* __restrict__ kb,
                                                       int* __restrict__ gcursor,
                                                       u64* __restrict__ edges,
                                                       int nnz, int binBlocks) {
    int t = threadIdx.x;
    if ((int)blockIdx.x >= binBlocks) {
        // ---- prep role: 8 floats per thread ----
        int base = ((blockIdx.x - binBlocks) * BIN_TPB + t) * 8;
        if (base + 8 <= NNODES * UNITS) {
            float4 fa = ((const float4*)(kf + base))[0];
            float4 fb = ((const float4*)(kf + base))[1];
            ushort4 oa, ob;
            oa.x = f2bf(__float_as_uint(fa.x)); oa.y = f2bf(__float_as_uint(fa.y));
            oa.z = f2bf(__float_as_uint(fa.z)); oa.w = f2bf(__float_as_uint(fa.w));
            ob.x = f2bf(__float_as_uint(fb.x)); ob.y = f2bf(__float_as_uint(fb.y));
            ob.z = f2bf(__float_as_uint(fb.z)); ob.w = f2bf(__float_as_uint(fb.w));
            ((ushort4*)(kb + base))[0] = oa;
            ((ushort4*)(kb + base))[1] = ob;
        }
        return;
    }

    // ---- bin role ----
    __shared__ u64 stage[BIN_TPB * BIN_EPT];   // 32 KB
    __shared__ int hist[NBUCK];
    __shared__ int lstart[NBUCK];
    __shared__ int delta[NBUCK];
    __shared__ int wsum[8];
    hist[t] = 0;
    __syncthreads();

    int blockStart = blockIdx.x * (BIN_TPB * BIN_EPT);
    int cnt = min(BIN_TPB * BIN_EPT, nnz - blockStart);
    int base_idx = blockStart + t * BIN_EPT;

    int rr[BIN_EPT];
    int cc[BIN_EPT];
    float vv[BIN_EPT];
    if (base_idx + BIN_EPT <= nnz) {
        int4 ra = ((const int4*)(rows + base_idx))[0];
        int4 rb = ((const int4*)(rows + base_idx))[1];
        int4 ca = ((const int4*)(cols + base_idx))[0];
        int4 cb = ((const int4*)(cols + base_idx))[1];
        float4 va = ((const float4*)(values + base_idx))[0];
        float4 vb = ((const float4*)(values + base_idx))[1];
        rr[0]=ra.x; rr[1]=ra.y; rr[2]=ra.z; rr[3]=ra.w;
        rr[4]=rb.x; rr[5]=rb.y; rr[6]=rb.z; rr[7]=rb.w;
        cc[0]=ca.x; cc[1]=ca.y; cc[2]=ca.z; cc[3]=ca.w;
        cc[4]=cb.x; cc[5]=cb.y; cc[6]=cb.z; cc[7]=cb.w;
        vv[0]=va.x; vv[1]=va.y; vv[2]=va.z; vv[3]=va.w;
        vv[4]=vb.x; vv[5]=vb.y; vv[6]=vb.z; vv[7]=vb.w;
    } else {
#pragma unroll
        for (int k = 0; k < BIN_EPT; ++k) {
            int idx = base_idx + k;
            rr[k] = (idx < nnz) ? rows[idx] : -1;
            cc[k] = (idx < nnz) ? cols[idx] : 0;
            vv[k] = (idx < nnz) ? values[idx] : 0.0f;
        }
    }

    u64 rec[BIN_EPT];
    int bk[BIN_EPT];
    int rk[BIN_EPT];
#pragma unroll
    for (int k = 0; k < BIN_EPT; ++k) {
        if (rr[k] >= 0) {
            int r = rr[k];
            u32 v = __float_as_uint(vv[k]);
            int b = (int)(((u32)r * 512u) / 50000u);
            int lrow = r - rowbase_of((u32)b);
            rec[k] = ((u64)v << 32) | ((u64)(u32)b << 23) | ((u64)(u32)lrow << 16) | (u64)(u32)cc[k];
            bk[k] = b;
            rk[k] = atomicAdd(&hist[b], 1);   // native ds_add
        } else {
            bk[k] = -1;
        }
    }
    __syncthreads();

    // shuffle-based exclusive scan of hist[0..512) -> lstart (8 waves x 64)
    {
        int wid = t >> 6, ln = t & 63;
        int val = hist[t];
        for (int off = 1; off < 64; off <<= 1) {
            int x = __shfl_up(val, off, 64);
            if (ln >= off) val += x;
        }
        if (ln == 63) wsum[wid] = val;
        __syncthreads();
        if (t == 0) {
            int s = 0;
            for (int i = 0; i < 8; ++i) { int x = wsum[i]; wsum[i] = s; s += x; }
        }
        __syncthreads();
        int incl = val + wsum[wid];
        int excl = incl - hist[t];
        int h = hist[t];
        int gbase = (h > 0) ? (t * CAP + atomicAdd(&gcursor[t], h)) : 0;
        delta[t] = gbase - excl;
        lstart[t] = excl;
    }
    __syncthreads();

#pragma unroll
    for (int k = 0; k < BIN_EPT; ++k) {
        if (bk[k] >= 0) stage[lstart[bk[k]] + rk[k]] = rec[k];
    }
    __syncthreads();

    for (int i = t; i < cnt; i += BIN_TPB) {
        u64 r = stage[i];
        int b = (int)((r >> 23) & 0x1FF);
        int gpos = delta[b] + i;
        if (gpos < (b + 1) * CAP) edges[gpos] = r;   // overflow insurance
    }
}

// One block per bucket. Phases 1-3 build a row-sorted record list in LDS.
// Phase 4: QUAD layout — lane&15 = unit quad (u64 bf16x4 load), lane>>4 =
// edge slot -> 4 edges per step, x4 unroll = 16 edges/iter, 4 loads in
// flight; 2 shfl_xor reduce; float4 store with fused bias+relu.
__global__ __launch_bounds__(SPMM_TPB) void gc_spmm(const u64* __restrict__ edges,
                                                    const int* __restrict__ gcursor,
                                                    const u16* __restrict__ kb,
                                                    const float* __restrict__ bias,
                                                    float* __restrict__ out) {
    __shared__ u64 stage[CAP];        // 28.7 KB
    __shared__ int rhist[128];
    __shared__ int rstart[129];
    __shared__ int wsum2[2];
    int b = blockIdx.x;
    int t = threadIdx.x;
    int rowlo = rowbase_of((u32)b);
    int nrows = rowbase_of((u32)b + 1u) - rowlo;   // 97 or 98
    int count = min(gcursor[b], CAP);
    const u64* eb = edges + (size_t)b * CAP;

    if (t < 128) rhist[t] = 0;
    __syncthreads();

    // Phase 1: load + rank (records stay in registers)
    u64 rec[4];
    int rk[4], lr[4];
#pragma unroll
    for (int k = 0; k < 4; ++k) {
        int i = k * SPMM_TPB + t;
        if (i < count) {
            u64 r = eb[i];
            rec[k] = r;
            int l = (int)((r >> 16) & 0x7F);
            lr[k] = l;
            rk[k] = atomicAdd(&rhist[l], 1);
        } else {
            lr[k] = -1;
        }
    }
    __syncthreads();

    // Phase 2: shuffle-based exclusive scan of rhist[0..128) -> rstart
    {
        int wid = t >> 6, ln = t & 63;
        int val = (t < 128) ? rhist[t] : 0;
        if (wid < 2) {
            for (int off = 1; off < 64; off <<= 1) {
                int x = __shfl_up(val, off, 64);
                if (ln >= off) val += x;
            }
            if (ln == 63) wsum2[wid] = val;
        }
        __syncthreads();
        if (t == 0) { int a = wsum2[0]; wsum2[0] = 0; wsum2[1] = a; }
        __syncthreads();
        if (wid < 2) rstart[t] = val + wsum2[wid] - rhist[t];
        if (t == 0) rstart[128] = count;
    }
    __syncthreads();

    // Phase 3: scatter to row-sorted LDS positions
#pragma unroll
    for (int k = 0; k < 4; ++k) {
        if (lr[k] >= 0) stage[rstart[lr[k]] + rk[k]] = rec[k];
    }
    __syncthreads();

    // Phase 4: 16 waves; wave handles rows w, w+16, ...
    int lane = t & 63;
    int ep = lane >> 4;              // edge slot 0..3
    int uq = lane & 15;              // unit quad: units 4uq..4uq+3
    int w = t >> 6;
    float4 bl = ((const float4*)bias)[uq];

    for (int row = w; row < nrows; row += 16) {
        int j0 = rstart[row];
        int e  = rstart[row + 1];
        float ax0=0.f, ay0=0.f, az0=0.f, aw0=0.f;
        float ax1=0.f, ay1=0.f, az1=0.f, aw1=0.f;
        float ax2=0.f, ay2=0.f, az2=0.f, aw2=0.f;
        float ax3=0.f, ay3=0.f, az3=0.f, aw3=0.f;
        int j = j0;
        for (; j + 16 <= e; j += 16) {
            u64 r0 = stage[j + 0  + ep];
            u64 r1 = stage[j + 4  + ep];
            u64 r2 = stage[j + 8  + ep];
            u64 r3 = stage[j + 12 + ep];
            u64 q0 = *(const u64*)(kb + ((u32)r0 & 0xFFFFu) * UNITS + 4 * uq);
            u64 q1 = *(const u64*)(kb + ((u32)r1 & 0xFFFFu) * UNITS + 4 * uq);
            u64 q2 = *(const u64*)(kb + ((u32)r2 & 0xFFFFu) * UNITS + 4 * uq);
            u64 q3 = *(const u64*)(kb + ((u32)r3 & 0xFFFFu) * UNITS + 4 * uq);
            float v0 = __uint_as_float((u32)(r0 >> 32));
            float v1 = __uint_as_float((u32)(r1 >> 32));
            float v2 = __uint_as_float((u32)(r2 >> 32));
            float v3 = __uint_as_float((u32)(r3 >> 32));
            u32 lo, hi;
            lo = (u32)q0; hi = (u32)(q0 >> 32);
            ax0 = fmaf(v0, __uint_as_float(lo << 16), ax0);
            ay0 = fmaf(v0, __uint_as_float(lo & 0xFFFF0000u), ay0);
            az0 = fmaf(v0, __uint_as_float(hi << 16), az0);
            aw0 = fmaf(v0, __uint_as_float(hi & 0xFFFF0000u), aw0);
            lo = (u32)q1; hi = (u32)(q1 >> 32);
            ax1 = fmaf(v1, __uint_as_float(lo << 16), ax1);
            ay1 = fmaf(v1, __uint_as_float(lo & 0xFFFF0000u), ay1);
            az1 = fmaf(v1, __uint_as_float(hi << 16), az1);
            aw1 = fmaf(v1, __uint_as_float(hi & 0xFFFF0000u), aw1);
            lo = (u32)q2; hi = (u32)(q2 >> 32);
            ax2 = fmaf(v2, __uint_as_float(lo << 16), ax2);
            ay2 = fmaf(v2, __uint_as_float(lo & 0xFFFF0000u), ay2);
            az2 = fmaf(v2, __uint_as_float(hi << 16), az2);
            aw2 = fmaf(v2, __uint_as_float(hi & 0xFFFF0000u), aw2);
            lo = (u32)q3; hi = (u32)(q3 >> 32);
            ax3 = fmaf(v3, __uint_as_float(lo << 16), ax3);
            ay3 = fmaf(v3, __uint_as_float(lo & 0xFFFF0000u), ay3);
            az3 = fmaf(v3, __uint_as_float(hi << 16), az3);
            aw3 = fmaf(v3, __uint_as_float(hi & 0xFFFF0000u), aw3);
        }
        // tail: 4 edges per step, guarded
        for (; j < e; j += 4) {
            int ji = j + ep;
            float v = 0.f;
            u64 q = 0;
            if (ji < e) {
                u64 r = stage[ji];
                q = *(const u64*)(kb + ((u32)r & 0xFFFFu) * UNITS + 4 * uq);
                v = __uint_as_float((u32)(r >> 32));
            }
            u32 lo = (u32)q, hi = (u32)(q >> 32);
            ax0 = fmaf(v, __uint_as_float(lo << 16), ax0);
            ay0 = fmaf(v, __uint_as_float(lo & 0xFFFF0000u), ay0);
            az0 = fmaf(v, __uint_as_float(hi << 16), az0);
            aw0 = fmaf(v, __uint_as_float(hi & 0xFFFF0000u), aw0);
        }
        float ax = (ax0 + ax1) + (ax2 + ax3);
        float ay = (ay0 + ay1) + (ay2 + ay3);
        float az = (az0 + az1) + (az2 + az3);
        float aw = (aw0 + aw1) + (aw2 + aw3);
        ax += __shfl_xor(ax, 16, 64); ax += __shfl_xor(ax, 32, 64);
        ay += __shfl_xor(ay, 16, 64); ay += __shfl_xor(ay, 32, 64);
        az += __shfl_xor(az, 16, 64); az += __shfl_xor(az, 32, 64);
        aw += __shfl_xor(aw, 16, 64); aw += __shfl_xor(aw, 32, 64);
        if (ep == 0) {
            float4 o;
            o.x = fmaxf(ax + bl.x, 0.0f);
            o.y = fmaxf(ay + bl.y, 0.0f);
            o.z = fmaxf(az + bl.z, 0.0f);
            o.w = fmaxf(aw + bl.w, 0.0f);
            ((float4*)out)[(size_t)(rowlo + row) * 16 + uq] = o;
        }
    }
}

extern "C" void kernel_launch(void* const* d_in, const int* in_sizes, int n_in,
                              void* d_out, int out_size, void* d_ws, size_t ws_size,
                              hipStream_t stream) {
    const int*   rows   = (const int*)d_in[0];
    const int*   cols   = (const int*)d_in[1];
    const float* values = (const float*)d_in[2];
    const float* kern   = (const float*)d_in[3];
    const float* bias   = (const float*)d_in[4];
    float* out = (float*)d_out;

    const int nnz = in_sizes[0];

    char* ws = (char*)d_ws;
    u16* kb      = (u16*)(ws + 0);
    int* gcursor = (int*)(ws + 6400000);
    u64* edges   = (u64*)(ws + 6402048);

    hipMemsetAsync(gcursor, 0, NBUCK * sizeof(int), stream);

    int binBlocks = (nnz + BIN_TPB * BIN_EPT - 1) / (BIN_TPB * BIN_EPT);  // 391
    gc_bin_prep<<<binBlocks + PREP_BLOCKS, BIN_TPB, 0, stream>>>(
        rows, cols, values, kern, kb, gcursor, edges, nnz, binBlocks);

    gc_spmm<<<NBUCK, SPMM_TPB, 0, stream>>>(edges, gcursor, kb, bias, out);
}